// Round 3
// baseline (619.082 us; speedup 1.0000x reference)
//
#include <hip/hip_runtime.h>

#define B_ 2
#define T_ 2048
#define D_ 2048
#define N_ 16
#define H_ 128
constexpr int WIN = 1024;

typedef __attribute__((ext_vector_type(8))) short s16x8;
typedef __attribute__((ext_vector_type(4))) float f32x4;

typedef const __attribute__((address_space(1))) void cglobal_void;
typedef __attribute__((address_space(3))) void lds_void;

__device__ __forceinline__ unsigned short f2b(float f) {
  union { float f; unsigned u; } v; v.f = f;
  unsigned r = v.u + 0x7FFFu + ((v.u >> 16) & 1u);
  return (unsigned short)(r >> 16);
}
__device__ __forceinline__ float b2f(unsigned short u) {
  union { unsigned u; float f; } v; v.u = ((unsigned)u) << 16;
  return v.f;
}

// ---------------------------------------------------------------------------
// Dtype detector: if inputs are fp32, the EVEN u16s (little-endian mantissa
// halves) have uniform bits -> ~40% show exponent-field >= 154. Real bf16
// activations (|v| < 2^27) show none. Writes count to *flag.
// ---------------------------------------------------------------------------
__global__ __launch_bounds__(256) void detect_kernel(
    const unsigned short* __restrict__ x, int* __restrict__ flag) {
  __shared__ int cnt[256];
  const int tid = threadIdx.x;
  int c = 0;
  for (int i = tid; i < 4096; i += 256) {
    const unsigned short u = x[2 * i];
    const int e = (u >> 7) & 0xFF;
    if (e >= 154) ++c;
  }
  cnt[tid] = c;
  __syncthreads();
  for (int s = 128; s > 0; s >>= 1) {
    if (tid < s) cnt[tid] += cnt[tid + s];
    __syncthreads();
  }
  if (tid == 0) *flag = cnt[0];
}

// ---------------------------------------------------------------------------
// x -> canonical bf16 (downcast fp32 or copy bf16, per flag)
// ---------------------------------------------------------------------------
__global__ __launch_bounds__(256) void convert_x_kernel(
    const void* __restrict__ src, unsigned short* __restrict__ dst,
    const int* __restrict__ flag, int n) {
  const int i = blockIdx.x * 256 + threadIdx.x;
  if (i >= n) return;
  const bool isf = (*flag > 64);
  dst[i] = isf ? f2b(((const float*)src)[i]) : ((const unsigned short*)src)[i];
}

// ---------------------------------------------------------------------------
// Batched tiled transpose with dtype adaptation:
// src (batch, R, C) -> dst (batch, C, R), output bf16.
// ---------------------------------------------------------------------------
__global__ __launch_bounds__(256) void transpose_kernel(
    const void* __restrict__ src, unsigned short* __restrict__ dst,
    int R, int C, const int* __restrict__ flag) {
  __shared__ unsigned short tile[32][33];
  const bool isf = (*flag > 64);
  const int c0 = blockIdx.x * 32, r0 = blockIdx.y * 32;
  const size_t base = (size_t)blockIdx.z * R * C;
  const int tx = threadIdx.x, ty = threadIdx.y;
#pragma unroll
  for (int j = 0; j < 32; j += 8) {
    const size_t idx = base + (size_t)(r0 + ty + j) * C + c0 + tx;
    tile[ty + j][tx] = isf ? f2b(((const float*)src)[idx])
                           : ((const unsigned short*)src)[idx];
  }
  __syncthreads();
#pragma unroll
  for (int j = 0; j < 32; j += 8)
    dst[base + (size_t)(c0 + ty + j) * R + r0 + tx] = tile[tx][ty + j];
}

// ---------------------------------------------------------------------------
// 128x128-tile bf16 GEMM, K=2048. A: [M][K] row-major bf16. Bt: pre-transposed
// bf16 weights (K contiguous per output-column row).
// mode 0: final projection; writes fp32 or bf16 to outp per *flag.
// mode 1: qkv scatter, always bf16 (internal); v stored transposed [h][t].
// ---------------------------------------------------------------------------
__global__ __launch_bounds__(256) void gemm128_kernel(
    const unsigned short* __restrict__ A,
    const unsigned short* __restrict__ Bt,
    void* __restrict__ outp,
    int mode, const int* __restrict__ flag) {
  constexpr int K = D_;
  __shared__ unsigned short As[128 * 32];
  __shared__ unsigned short Bs[128 * 32];
  const int tid = threadIdx.x;
  const int wave = tid >> 6, lane = tid & 63;
  const int lr = lane & 15, lq = lane >> 4;
  const int wm = (wave >> 1) * 64, wn = (wave & 1) * 64;
  const size_t m0 = (size_t)blockIdx.x * 128;
  const unsigned short* pA = A + m0 * K;
  const unsigned short* pB = Bt + (size_t)blockIdx.y * 128 * K;

  f32x4 acc[4][4] = {};

  const int cA = tid, cB = 256 + tid;
  const int row0 = cA >> 2, col0 = (cA & 3) * 8;
  const int row1 = cB >> 2, col1 = (cB & 3) * 8;
  unsigned short* lA0 = As + (size_t)(wave * 64) * 8;
  unsigned short* lA1 = As + (size_t)(256 + wave * 64) * 8;
  unsigned short* lB0 = Bs + (size_t)(wave * 64) * 8;
  unsigned short* lB1 = Bs + (size_t)(256 + wave * 64) * 8;

  for (int k0 = 0; k0 < K; k0 += 32) {
    __syncthreads();
    __builtin_amdgcn_global_load_lds((cglobal_void*)(pA + (size_t)row0 * K + k0 + col0),
                                     (lds_void*)lA0, 16, 0, 0);
    __builtin_amdgcn_global_load_lds((cglobal_void*)(pA + (size_t)row1 * K + k0 + col1),
                                     (lds_void*)lA1, 16, 0, 0);
    __builtin_amdgcn_global_load_lds((cglobal_void*)(pB + (size_t)row0 * K + k0 + col0),
                                     (lds_void*)lB0, 16, 0, 0);
    __builtin_amdgcn_global_load_lds((cglobal_void*)(pB + (size_t)row1 * K + k0 + col1),
                                     (lds_void*)lB1, 16, 0, 0);
    __syncthreads();
    s16x8 af[4], bfr[4];
#pragma unroll
    for (int mb = 0; mb < 4; ++mb)
      af[mb] = *(const s16x8*)(As + (wm + mb * 16 + lr) * 32 + lq * 8);
#pragma unroll
    for (int nb = 0; nb < 4; ++nb)
      bfr[nb] = *(const s16x8*)(Bs + (wn + nb * 16 + lr) * 32 + lq * 8);
#pragma unroll
    for (int mb = 0; mb < 4; ++mb)
#pragma unroll
      for (int nb = 0; nb < 4; ++nb)
        acc[mb][nb] = __builtin_amdgcn_mfma_f32_16x16x32_bf16(af[mb], bfr[nb], acc[mb][nb], 0, 0, 0);
  }

  if (mode == 0) {
    const bool isf = (*flag > 64);
#pragma unroll
    for (int mb = 0; mb < 4; ++mb) {
      const size_t r = m0 + wm + mb * 16 + lq * 4;
#pragma unroll
      for (int nb = 0; nb < 4; ++nb) {
        const size_t c = (size_t)blockIdx.y * 128 + wn + nb * 16 + lr;
#pragma unroll
        for (int i = 0; i < 4; ++i) {
          if (isf) ((float*)outp)[(r + i) * D_ + c] = acc[mb][nb][i];
          else ((unsigned short*)outp)[(r + i) * D_ + c] = f2b(acc[mb][nb][i]);
        }
      }
    }
  } else {
    unsigned short* op = (unsigned short*)outp;
    const int s = blockIdx.y >> 4, n = blockIdx.y & 15;
    const size_t SB = (size_t)B_ * N_ * T_ * H_;
#pragma unroll
    for (int mb = 0; mb < 4; ++mb) {
#pragma unroll
      for (int i = 0; i < 4; ++i) {
        const size_t r = m0 + wm + mb * 16 + lq * 4 + i;
        const int b = (int)(r >> 11);
        const int t = (int)(r & 2047);
        const size_t base = s * SB + (size_t)(b * N_ + n) * T_ * H_;
#pragma unroll
        for (int nb = 0; nb < 4; ++nb) {
          const int h = wn + nb * 16 + lr;
          size_t idx = (s < 2) ? (base + (size_t)t * H_ + h)
                               : (base + (size_t)h * T_ + t);
          op[idx] = f2b(acc[mb][nb][i]);
        }
      }
    }
  }
}

// ---------------------------------------------------------------------------
// RoPE in place on q,k rows. One wave per 128-elem row; q scaled by H^-0.5.
// ---------------------------------------------------------------------------
__global__ __launch_bounds__(256) void rope_kernel(unsigned short* __restrict__ qk) {
  const int tid = threadIdx.x;
  const int lane = tid & 63;
  const size_t row = (size_t)blockIdx.x * 4 + (tid >> 6);
  const int t = (int)(row & (T_ - 1));
  const int s = (int)(row >> 16);
  unsigned short* p = qk + row * H_;
  float x1 = b2f(p[lane]), x2 = b2f(p[lane + 64]);
  float inv_ts = powf(10000.0f, -((float)lane) * (1.0f / 64.0f));
  float sv, cv;
  sincosf((float)t * inv_ts, &sv, &cv);
  float o1 = x1 * cv - x2 * sv;
  float o2 = x2 * cv + x1 * sv;
  if (s == 0) { o1 *= 0.08838834764831845f; o2 *= 0.08838834764831845f; }
  p[lane] = f2b(o1);
  p[lane + 64] = f2b(o2);
}

// ---------------------------------------------------------------------------
// Flash attention: block = (64-query tile, b*16+n). 4 waves, 16 queries/wave.
// ---------------------------------------------------------------------------
__global__ __launch_bounds__(256) void attn_kernel(
    const unsigned short* __restrict__ qkv, unsigned short* __restrict__ enc) {
  const int tid = threadIdx.x, lane = tid & 63, wave = tid >> 6;
  const int lr = lane & 15, lq = lane >> 4;
  const int bn = blockIdx.y;
  const int b = bn >> 4, n = bn & 15;
  const int t0 = blockIdx.x * 64;
  const size_t SB = (size_t)B_ * N_ * T_ * H_;
  const unsigned short* qp = qkv + (size_t)bn * T_ * H_;
  const unsigned short* kp = qp + SB;
  const unsigned short* vp = qp + 2 * SB;  // [h][t]

  __shared__ unsigned short Ks[64 * 136];
  __shared__ unsigned short Vt[128 * 72];
  __shared__ unsigned short Ps[4][16 * 72];

  s16x8 aq[4];
  {
    const int t = t0 + wave * 16 + lr;
#pragma unroll
    for (int kc = 0; kc < 4; ++kc)
      aq[kc] = *(const s16x8*)(qp + (size_t)t * H_ + kc * 32 + lq * 8);
  }

  f32x4 oacc[8] = {};
  float m_i[4], l_i[4];
#pragma unroll
  for (int i = 0; i < 4; ++i) { m_i[i] = -20000.0f; l_i[i] = 0.0f; }

  const int s_lo = (t0 >= WIN - 1) ? ((t0 - (WIN - 1)) & ~63) : 0;

  for (int s0 = s_lo; s0 <= t0 + 63; s0 += 64) {
    __syncthreads();
#pragma unroll
    for (int j = 0; j < 4; ++j) {
      const int c = j * 256 + tid;
      const int row = c >> 4, col = (c & 15) * 8;
      *(s16x8*)(Ks + row * 136 + col) = *(const s16x8*)(kp + (size_t)(s0 + row) * H_ + col);
    }
#pragma unroll
    for (int j = 0; j < 4; ++j) {
      const int c = j * 256 + tid;
      const int row = c >> 3, col = (c & 7) * 8;
      *(s16x8*)(Vt + row * 72 + col) = *(const s16x8*)(vp + (size_t)row * T_ + s0 + col);
    }
    __syncthreads();

    float sc[4][4];
#pragma unroll
    for (int sb = 0; sb < 4; ++sb) {
      f32x4 a = {};
#pragma unroll
      for (int kc = 0; kc < 4; ++kc) {
        s16x8 bk = *(const s16x8*)(Ks + (sb * 16 + lr) * 136 + kc * 32 + lq * 8);
        a = __builtin_amdgcn_mfma_f32_16x16x32_bf16(aq[kc], bk, a, 0, 0, 0);
      }
      const int key = s0 + sb * 16 + lr;
#pragma unroll
      for (int i = 0; i < 4; ++i) {
        const int t = t0 + wave * 16 + lq * 4 + i;
        float z = a[i] * 0.02f;
        z = fminf(fmaxf(z, -15.0f), 15.0f);
        const float e = __expf(2.0f * z);
        const float capped = 50.0f * (e - 1.0f) / (e + 1.0f);
        const bool ok = (key <= t) && (key >= t - (WIN - 1));
        sc[sb][i] = ok ? capped : -30000.0f;
      }
    }

    float alpha[4];
#pragma unroll
    for (int i = 0; i < 4; ++i) {
      float mx = fmaxf(fmaxf(sc[0][i], sc[1][i]), fmaxf(sc[2][i], sc[3][i]));
#pragma unroll
      for (int off = 1; off < 16; off <<= 1)
        mx = fmaxf(mx, __shfl_xor(mx, off, 64));
      const float mn = fmaxf(m_i[i], mx);
      alpha[i] = __expf(m_i[i] - mn);
      m_i[i] = mn;
      float rs = 0.0f;
#pragma unroll
      for (int sb = 0; sb < 4; ++sb) {
        const float pv = __expf(sc[sb][i] - mn);
        sc[sb][i] = pv;
        rs += pv;
      }
#pragma unroll
      for (int off = 1; off < 16; off <<= 1)
        rs += __shfl_xor(rs, off, 64);
      l_i[i] = l_i[i] * alpha[i] + rs;
    }
#pragma unroll
    for (int hb = 0; hb < 8; ++hb)
#pragma unroll
      for (int i = 0; i < 4; ++i) oacc[hb][i] *= alpha[i];

    unsigned short* ps = Ps[wave];
#pragma unroll
    for (int sb = 0; sb < 4; ++sb)
#pragma unroll
      for (int i = 0; i < 4; ++i)
        ps[(lq * 4 + i) * 72 + sb * 16 + lr] = f2b(sc[sb][i]);
    __syncthreads();
    s16x8 ap[2];
#pragma unroll
    for (int kc = 0; kc < 2; ++kc)
      ap[kc] = *(const s16x8*)(ps + lr * 72 + kc * 32 + lq * 8);

#pragma unroll
    for (int hb = 0; hb < 8; ++hb) {
#pragma unroll
      for (int kc = 0; kc < 2; ++kc) {
        s16x8 bv = *(const s16x8*)(Vt + (hb * 16 + lr) * 72 + kc * 32 + lq * 8);
        oacc[hb] = __builtin_amdgcn_mfma_f32_16x16x32_bf16(ap[kc], bv, oacc[hb], 0, 0, 0);
      }
    }
  }

#pragma unroll
  for (int i = 0; i < 4; ++i) {
    const int t = t0 + wave * 16 + lq * 4 + i;
    const float inv = 1.0f / l_i[i];
    const size_t rowb = ((size_t)b * T_ + t) * (N_ * H_) + (size_t)n * H_;
#pragma unroll
    for (int hb = 0; hb < 8; ++hb)
      enc[rowb + hb * 16 + lr] = f2b(oacc[hb][i] * inv);
  }
}

// ---------------------------------------------------------------------------
extern "C" void kernel_launch(void* const* d_in, const int* in_sizes, int n_in,
                              void* d_out, int out_size, void* d_ws, size_t ws_size,
                              hipStream_t stream) {
  const void* x     = d_in[0];  // (B,T,D)    fp32 (auto-detected; bf16 hedge)
  const void* w_qkv = d_in[1];  // (3,N,D,H)
  const void* w_out = d_in[2];  // (N,H,D)

  // workspace layout (bytes), aliased, peak 88 MB:
  //   [0,64)        flag
  //   [64,+16MB)    xc  (bf16 x)      -> later woutT
  //   [+16,+40MB)   wqkvT (24MB)      -> later enc
  //   [+40,+88MB)   qkv (48MB)
  char* wsb = (char*)d_ws;
  int* flag = (int*)wsb;
  unsigned short* xc    = (unsigned short*)(wsb + 64);
  unsigned short* wqkvT = (unsigned short*)(wsb + 64 + 16777216);
  unsigned short* qkv   = (unsigned short*)(wsb + 64 + 16777216 + 25165824);
  unsigned short* woutT = xc;     // reuse after QKV GEMM consumed xc
  unsigned short* enc   = wqkvT;  // reuse after QKV GEMM consumed wqkvT

  detect_kernel<<<1, 256, 0, stream>>>((const unsigned short*)x, flag);
  convert_x_kernel<<<32768, 256, 0, stream>>>(x, xc, flag, B_ * T_ * D_);
  transpose_kernel<<<dim3(4, 64, 48), dim3(32, 8), 0, stream>>>(w_qkv, wqkvT, 2048, 128, flag);
  gemm128_kernel<<<dim3(32, 48), 256, 0, stream>>>(xc, wqkvT, qkv, 1, flag);
  rope_kernel<<<32768, 256, 0, stream>>>(qkv);
  transpose_kernel<<<dim3(64, 64, 1), dim3(32, 8), 0, stream>>>(w_out, woutT, 2048, 2048, flag);
  attn_kernel<<<dim3(32, 32), 256, 0, stream>>>(qkv, enc);
  gemm128_kernel<<<dim3(32, 16), 256, 0, stream>>>(enc, woutT, d_out, 0, flag);
}

// Round 4
// 512.071 us; speedup vs baseline: 1.2090x; 1.2090x over previous
//
#include <hip/hip_runtime.h>

#define B_ 2
#define T_ 2048
#define D_ 2048
#define N_ 16
#define H_ 128
constexpr int WIN = 1024;

typedef __attribute__((ext_vector_type(8))) short s16x8;
typedef __attribute__((ext_vector_type(4))) float f32x4;

typedef const __attribute__((address_space(1))) void cglobal_void;
typedef __attribute__((address_space(3))) void lds_void;

__device__ __forceinline__ unsigned short f2b(float f) {
  union { float f; unsigned u; } v; v.f = f;
  unsigned r = v.u + 0x7FFFu + ((v.u >> 16) & 1u);
  return (unsigned short)(r >> 16);
}
__device__ __forceinline__ float b2f(unsigned short u) {
  union { unsigned u; float f; } v; v.u = ((unsigned)u) << 16;
  return v.f;
}

// ---------------------------------------------------------------------------
// Dtype detector (fp32 vs bf16 inputs) — see round-2 notes. fp32 mantissa
// halves look like big exponents ~40% of the time; bf16 activations never.
// ---------------------------------------------------------------------------
__global__ __launch_bounds__(256) void detect_kernel(
    const unsigned short* __restrict__ x, int* __restrict__ flag) {
  __shared__ int cnt[256];
  const int tid = threadIdx.x;
  int c = 0;
  for (int i = tid; i < 4096; i += 256) {
    const unsigned short u = x[2 * i];
    const int e = (u >> 7) & 0xFF;
    if (e >= 154) ++c;
  }
  cnt[tid] = c;
  __syncthreads();
  for (int s = 128; s > 0; s >>= 1) {
    if (tid < s) cnt[tid] += cnt[tid + s];
    __syncthreads();
  }
  if (tid == 0) *flag = cnt[0];
}

__global__ __launch_bounds__(256) void convert_x_kernel(
    const void* __restrict__ src, unsigned short* __restrict__ dst,
    const int* __restrict__ flag, int n) {
  const int i = blockIdx.x * 256 + threadIdx.x;
  if (i >= n) return;
  const bool isf = (*flag > 64);
  dst[i] = isf ? f2b(((const float*)src)[i]) : ((const unsigned short*)src)[i];
}

// ---------------------------------------------------------------------------
// Batched tiled transpose, dtype-adaptive input, bf16 out.
// ---------------------------------------------------------------------------
__global__ __launch_bounds__(256) void transpose_kernel(
    const void* __restrict__ src, unsigned short* __restrict__ dst,
    int R, int C, const int* __restrict__ flag) {
  __shared__ unsigned short tile[32][33];
  const bool isf = (*flag > 64);
  const int c0 = blockIdx.x * 32, r0 = blockIdx.y * 32;
  const size_t base = (size_t)blockIdx.z * R * C;
  const int tx = threadIdx.x, ty = threadIdx.y;
#pragma unroll
  for (int j = 0; j < 32; j += 8) {
    const size_t idx = base + (size_t)(r0 + ty + j) * C + c0 + tx;
    tile[ty + j][tx] = isf ? f2b(((const float*)src)[idx])
                           : ((const unsigned short*)src)[idx];
  }
  __syncthreads();
#pragma unroll
  for (int j = 0; j < 32; j += 8)
    dst[base + (size_t)(c0 + ty + j) * R + r0 + tx] = tile[tx][ty + j];
}

// bf16-only batched transpose (for V [t][h] -> [h][t] per (b,n))
__global__ __launch_bounds__(256) void transpose_bf16_kernel(
    const unsigned short* __restrict__ src, unsigned short* __restrict__ dst,
    int R, int C) {
  __shared__ unsigned short tile[32][33];
  const int c0 = blockIdx.x * 32, r0 = blockIdx.y * 32;
  const size_t base = (size_t)blockIdx.z * R * C;
  const int tx = threadIdx.x, ty = threadIdx.y;
#pragma unroll
  for (int j = 0; j < 32; j += 8)
    tile[ty + j][tx] = src[base + (size_t)(r0 + ty + j) * C + c0 + tx];
  __syncthreads();
#pragma unroll
  for (int j = 0; j < 32; j += 8)
    dst[base + (size_t)(c0 + ty + j) * R + r0 + tx] = tile[tx][ty + j];
}

// ---------------------------------------------------------------------------
// 128x128-tile bf16 GEMM, K=2048 (m97 structure).
// mode 0: final projection, fp32/bf16 out per flag. mode 1: qkv, [s][b][n][t][h].
// ---------------------------------------------------------------------------
__global__ __launch_bounds__(256) void gemm128_kernel(
    const unsigned short* __restrict__ A,
    const unsigned short* __restrict__ Bt,
    void* __restrict__ outp,
    int mode, const int* __restrict__ flag) {
  constexpr int K = D_;
  __shared__ unsigned short As[128 * 32];
  __shared__ unsigned short Bs[128 * 32];
  const int tid = threadIdx.x;
  const int wave = tid >> 6, lane = tid & 63;
  const int lr = lane & 15, lq = lane >> 4;
  const int wm = (wave >> 1) * 64, wn = (wave & 1) * 64;
  const size_t m0 = (size_t)blockIdx.x * 128;
  const unsigned short* pA = A + m0 * K;
  const unsigned short* pB = Bt + (size_t)blockIdx.y * 128 * K;

  f32x4 acc[4][4] = {};

  const int cA = tid, cB = 256 + tid;
  const int row0 = cA >> 2, col0 = (cA & 3) * 8;
  const int row1 = cB >> 2, col1 = (cB & 3) * 8;
  unsigned short* lA0 = As + (size_t)(wave * 64) * 8;
  unsigned short* lA1 = As + (size_t)(256 + wave * 64) * 8;
  unsigned short* lB0 = Bs + (size_t)(wave * 64) * 8;
  unsigned short* lB1 = Bs + (size_t)(256 + wave * 64) * 8;

  for (int k0 = 0; k0 < K; k0 += 32) {
    __syncthreads();
    __builtin_amdgcn_global_load_lds((cglobal_void*)(pA + (size_t)row0 * K + k0 + col0),
                                     (lds_void*)lA0, 16, 0, 0);
    __builtin_amdgcn_global_load_lds((cglobal_void*)(pA + (size_t)row1 * K + k0 + col1),
                                     (lds_void*)lA1, 16, 0, 0);
    __builtin_amdgcn_global_load_lds((cglobal_void*)(pB + (size_t)row0 * K + k0 + col0),
                                     (lds_void*)lB0, 16, 0, 0);
    __builtin_amdgcn_global_load_lds((cglobal_void*)(pB + (size_t)row1 * K + k0 + col1),
                                     (lds_void*)lB1, 16, 0, 0);
    __syncthreads();
    s16x8 af[4], bfr[4];
#pragma unroll
    for (int mb = 0; mb < 4; ++mb)
      af[mb] = *(const s16x8*)(As + (wm + mb * 16 + lr) * 32 + lq * 8);
#pragma unroll
    for (int nb = 0; nb < 4; ++nb)
      bfr[nb] = *(const s16x8*)(Bs + (wn + nb * 16 + lr) * 32 + lq * 8);
#pragma unroll
    for (int mb = 0; mb < 4; ++mb)
#pragma unroll
      for (int nb = 0; nb < 4; ++nb)
        acc[mb][nb] = __builtin_amdgcn_mfma_f32_16x16x32_bf16(af[mb], bfr[nb], acc[mb][nb], 0, 0, 0);
  }

  if (mode == 0) {
    const bool isf = (*flag > 64);
#pragma unroll
    for (int mb = 0; mb < 4; ++mb) {
      const size_t r = m0 + wm + mb * 16 + lq * 4;
#pragma unroll
      for (int nb = 0; nb < 4; ++nb) {
        const size_t c = (size_t)blockIdx.y * 128 + wn + nb * 16 + lr;
#pragma unroll
        for (int i = 0; i < 4; ++i) {
          if (isf) ((float*)outp)[(r + i) * D_ + c] = acc[mb][nb][i];
          else ((unsigned short*)outp)[(r + i) * D_ + c] = f2b(acc[mb][nb][i]);
        }
      }
    }
  } else {
    unsigned short* op = (unsigned short*)outp;
    const int s = blockIdx.y >> 4, n = blockIdx.y & 15;
    const size_t SB = (size_t)B_ * N_ * T_ * H_;
#pragma unroll
    for (int mb = 0; mb < 4; ++mb) {
#pragma unroll
      for (int i = 0; i < 4; ++i) {
        const size_t r = m0 + wm + mb * 16 + lq * 4 + i;
        const int b = (int)(r >> 11);
        const int t = (int)(r & 2047);
        const size_t base = s * SB + (size_t)(b * N_ + n) * T_ * H_ + (size_t)t * H_;
#pragma unroll
        for (int nb = 0; nb < 4; ++nb)
          op[base + wn + nb * 16 + lr] = f2b(acc[mb][nb][i]);
      }
    }
  }
}

// ---------------------------------------------------------------------------
// RoPE in place on q,k rows. One wave per 128-elem row; q scaled by H^-0.5.
// ---------------------------------------------------------------------------
__global__ __launch_bounds__(256) void rope_kernel(unsigned short* __restrict__ qk) {
  const int tid = threadIdx.x;
  const int lane = tid & 63;
  const size_t row = (size_t)blockIdx.x * 4 + (tid >> 6);
  const int t = (int)(row & (T_ - 1));
  const int s = (int)(row >> 16);
  unsigned short* p = qk + row * H_;
  float x1 = b2f(p[lane]), x2 = b2f(p[lane + 64]);
  float inv_ts = powf(10000.0f, -((float)lane) * (1.0f / 64.0f));
  float sv, cv;
  sincosf((float)t * inv_ts, &sv, &cv);
  float o1 = x1 * cv - x2 * sv;
  float o2 = x2 * cv + x1 * sv;
  if (s == 0) { o1 *= 0.08838834764831845f; o2 *= 0.08838834764831845f; }
  p[lane] = f2b(o1);
  p[lane + 64] = f2b(o2);
}

// ---------------------------------------------------------------------------
// Flash attention. Softcap bounds logits at +-50 => FIXED softmax offset m=12:
// p = exp(capped-12). No online max, no rescale; l deferred to epilogue.
// Grid: (x=bn 32, y=t-tile 32) for CU load balance. Ps aliases Ks (4th barrier)
// => LDS 35840 B => 4 blocks/CU.
// ---------------------------------------------------------------------------
__global__ __launch_bounds__(256, 4) void attn_kernel(
    const unsigned short* __restrict__ qkv,
    const unsigned short* __restrict__ vt,
    unsigned short* __restrict__ enc) {
  const int tid = threadIdx.x, lane = tid & 63, wave = tid >> 6;
  const int lr = lane & 15, lq = lane >> 4;
  const int bn = blockIdx.x;
  const int b = bn >> 4, n = bn & 15;
  const int t0 = blockIdx.y * 64;
  const size_t SB = (size_t)B_ * N_ * T_ * H_;
  const unsigned short* qp = qkv + (size_t)bn * T_ * H_;
  const unsigned short* kp = qp + SB;
  const unsigned short* vp = vt + (size_t)bn * T_ * H_;  // [h][t]

  __shared__ unsigned short Ks[64 * 136];  // [key][h]; Ps aliases this
  __shared__ unsigned short Vt[128 * 72];  // [h][key]
  unsigned short* Ps = Ks + wave * (16 * 136);  // per-wave 16x64, stride 136

  // Q fragments (A-layout), registers for whole kernel
  s16x8 aq[4];
  {
    const int t = t0 + wave * 16 + lr;
#pragma unroll
    for (int kc = 0; kc < 4; ++kc)
      aq[kc] = *(const s16x8*)(qp + (size_t)t * H_ + kc * 32 + lq * 8);
  }

  f32x4 oacc[8] = {};
  float lp[4] = {0.f, 0.f, 0.f, 0.f};  // per-lane l partials

  const int s_lo = (t0 >= WIN - 1) ? ((t0 - (WIN - 1)) & ~63) : 0;
  constexpr float C_IN = 2.885390082f / 50.0f;  // 2*log2(e)/SOFT_CAP
  constexpr float C_T = 50.0f * 1.442695041f;   // SOFT_CAP*log2(e)
  constexpr float C_OFF = 12.0f * 1.442695041f; // m*log2(e)

  for (int s0 = s_lo; s0 <= t0 + 63; s0 += 64) {
    __syncthreads();  // (A) prev-iter Ps/Vt reads done before restage
#pragma unroll
    for (int j = 0; j < 4; ++j) {
      const int c = j * 256 + tid;
      const int row = c >> 4, col = (c & 15) * 8;
      *(s16x8*)(Ks + row * 136 + col) = *(const s16x8*)(kp + (size_t)(s0 + row) * H_ + col);
    }
#pragma unroll
    for (int j = 0; j < 4; ++j) {
      const int c = j * 256 + tid;
      const int row = c >> 3, col = (c & 7) * 8;
      *(s16x8*)(Vt + row * 72 + col) = *(const s16x8*)(vp + (size_t)row * T_ + s0 + col);
    }
    __syncthreads();  // (B) staging visible

    // QK^T -> softcap -> p = exp2(C_T*tanh - C_OFF)
    float p[4][4];
#pragma unroll
    for (int sb = 0; sb < 4; ++sb) {
      f32x4 a = {};
#pragma unroll
      for (int kc = 0; kc < 4; ++kc) {
        s16x8 bk = *(const s16x8*)(Ks + (sb * 16 + lr) * 136 + kc * 32 + lq * 8);
        a = __builtin_amdgcn_mfma_f32_16x16x32_bf16(aq[kc], bk, a, 0, 0, 0);
      }
#pragma unroll
      for (int i = 0; i < 4; ++i) {
        float zz = a[i] * C_IN;
        zz = fminf(fmaxf(zz, -44.0f), 44.0f);
        const float u = exp2f(zz);
        const float th = (u - 1.0f) * __builtin_amdgcn_rcpf(u + 1.0f);
        p[sb][i] = exp2f(th * C_T - C_OFF);
      }
    }

    // mask only on boundary tiles (wave-uniform branch)
    const bool interior = (s0 + 63 <= t0) && (s0 >= t0 + 63 - (WIN - 1));
    if (!interior) {
#pragma unroll
      for (int sb = 0; sb < 4; ++sb) {
        const int key = s0 + sb * 16 + lr;
#pragma unroll
        for (int i = 0; i < 4; ++i) {
          const int t = t0 + wave * 16 + lq * 4 + i;
          if (key > t || key < t - (WIN - 1)) p[sb][i] = 0.0f;
        }
      }
    }
#pragma unroll
    for (int sb = 0; sb < 4; ++sb)
#pragma unroll
      for (int i = 0; i < 4; ++i) lp[i] += p[sb][i];

    __syncthreads();  // (C) all QK reads of Ks done before Ps overwrite
#pragma unroll
    for (int sb = 0; sb < 4; ++sb)
#pragma unroll
      for (int i = 0; i < 4; ++i)
        Ps[(lq * 4 + i) * 136 + sb * 16 + lr] = f2b(p[sb][i]);
    __syncthreads();  // (D) Ps visible

    s16x8 ap[2];
#pragma unroll
    for (int kc = 0; kc < 2; ++kc)
      ap[kc] = *(const s16x8*)(Ps + lr * 136 + kc * 32 + lq * 8);

#pragma unroll
    for (int hb = 0; hb < 8; ++hb) {
#pragma unroll
      for (int kc = 0; kc < 2; ++kc) {
        s16x8 bv = *(const s16x8*)(Vt + (hb * 16 + lr) * 72 + kc * 32 + lq * 8);
        oacc[hb] = __builtin_amdgcn_mfma_f32_16x16x32_bf16(ap[kc], bv, oacc[hb], 0, 0, 0);
      }
    }
  }

  // l: reduce per-lane partials across the 16 lr-lanes (stays within quarter)
#pragma unroll
  for (int i = 0; i < 4; ++i) {
#pragma unroll
    for (int off = 1; off < 16; off <<= 1)
      lp[i] += __shfl_xor(lp[i], off, 64);
  }

#pragma unroll
  for (int i = 0; i < 4; ++i) {
    const int t = t0 + wave * 16 + lq * 4 + i;
    const float inv = 1.0f / lp[i];
    const size_t rowb = ((size_t)b * T_ + t) * (N_ * H_) + (size_t)n * H_;
#pragma unroll
    for (int hb = 0; hb < 8; ++hb)
      enc[rowb + hb * 16 + lr] = f2b(oacc[hb][i] * inv);
  }
}

// ---------------------------------------------------------------------------
extern "C" void kernel_launch(void* const* d_in, const int* in_sizes, int n_in,
                              void* d_out, int out_size, void* d_ws, size_t ws_size,
                              hipStream_t stream) {
  const void* x     = d_in[0];  // (B,T,D)    fp32 (auto-detected; bf16 hedge)
  const void* w_qkv = d_in[1];  // (3,N,D,H)
  const void* w_out = d_in[2];  // (N,H,D)

  // workspace (88 MB peak, proven safe in round 2):
  //   [0,64)          flag
  //   A [64,+16MB)    xc        -> later vt (v transposed, 16MB)
  //   B [+16,+40MB)   wqkvT     -> later enc(16MB) + woutT(8MB)
  //   C [+40,+88MB)   qkv: q(16) k(16) v(16)
  char* wsb = (char*)d_ws;
  int* flag = (int*)wsb;
  const size_t MB = 1048576;
  unsigned short* xc    = (unsigned short*)(wsb + 64);
  unsigned short* wqkvT = (unsigned short*)(wsb + 64 + 16 * MB);
  unsigned short* qkv   = (unsigned short*)(wsb + 64 + 40 * MB);
  unsigned short* vt    = xc;                                        // alias
  unsigned short* enc   = wqkvT;                                     // alias
  unsigned short* woutT = (unsigned short*)(wsb + 64 + 32 * MB);     // alias
  unsigned short* v     = qkv + 2 * (size_t)B_ * N_ * T_ * H_;

  detect_kernel<<<1, 256, 0, stream>>>((const unsigned short*)x, flag);
  convert_x_kernel<<<32768, 256, 0, stream>>>(x, xc, flag, B_ * T_ * D_);
  transpose_kernel<<<dim3(4, 64, 48), dim3(32, 8), 0, stream>>>(w_qkv, wqkvT, 2048, 128, flag);
  gemm128_kernel<<<dim3(32, 48), 256, 0, stream>>>(xc, wqkvT, qkv, 1, flag);
  rope_kernel<<<32768, 256, 0, stream>>>(qkv);
  // v [t][h] -> vt [h][t], 32 (b,n) batches; xc dead, wqkvT dead after gemm
  transpose_bf16_kernel<<<dim3(4, 64, 32), dim3(32, 8), 0, stream>>>(v, vt, 2048, 128);
  transpose_kernel<<<dim3(64, 64, 1), dim3(32, 8), 0, stream>>>(w_out, woutT, 2048, 2048, flag);
  attn_kernel<<<dim3(32, 32), 256, 0, stream>>>(qkv, vt, enc);
  gemm128_kernel<<<dim3(32, 16), 256, 0, stream>>>(enc, woutT, d_out, 0, flag);
}

// Round 5
// 458.985 us; speedup vs baseline: 1.3488x; 1.1157x over previous
//
#include <hip/hip_runtime.h>

#define B_ 2
#define T_ 2048
#define D_ 2048
#define N_ 16
#define H_ 128
constexpr int WIN = 1024;

typedef __attribute__((ext_vector_type(8))) short s16x8;
typedef __attribute__((ext_vector_type(4))) float f32x4;
typedef __attribute__((ext_vector_type(4))) unsigned short u16x4;

typedef const __attribute__((address_space(1))) void cglobal_void;
typedef __attribute__((address_space(3))) void lds_void;

__device__ __forceinline__ unsigned short f2b(float f) {
  union { float f; unsigned u; } v; v.f = f;
  unsigned r = v.u + 0x7FFFu + ((v.u >> 16) & 1u);
  return (unsigned short)(r >> 16);
}
__device__ __forceinline__ float b2f(unsigned short u) {
  union { unsigned u; float f; } v; v.u = ((unsigned)u) << 16;
  return v.f;
}

// ---------------------------------------------------------------------------
// Dtype detector (fp32 vs bf16 inputs): fp32 mantissa halves look like big
// exponents ~40% of the time; bf16 activations never.
// ---------------------------------------------------------------------------
__global__ __launch_bounds__(256) void detect_kernel(
    const unsigned short* __restrict__ x, int* __restrict__ flag) {
  __shared__ int cnt[256];
  const int tid = threadIdx.x;
  int c = 0;
  for (int i = tid; i < 4096; i += 256) {
    const unsigned short u = x[2 * i];
    const int e = (u >> 7) & 0xFF;
    if (e >= 154) ++c;
  }
  cnt[tid] = c;
  __syncthreads();
  for (int s = 128; s > 0; s >>= 1) {
    if (tid < s) cnt[tid] += cnt[tid + s];
    __syncthreads();
  }
  if (tid == 0) *flag = cnt[0];
}

// x -> canonical bf16, 4 elems/thread
__global__ __launch_bounds__(256) void convert_x_kernel(
    const void* __restrict__ src, unsigned short* __restrict__ dst,
    const int* __restrict__ flag, int n4) {
  const int i = blockIdx.x * 256 + threadIdx.x;
  if (i >= n4) return;
  const bool isf = (*flag > 64);
  u16x4 o;
  if (isf) {
    const float4 f = ((const float4*)src)[i];
    o[0] = f2b(f.x); o[1] = f2b(f.y); o[2] = f2b(f.z); o[3] = f2b(f.w);
  } else {
    o = ((const u16x4*)src)[i];
  }
  *(u16x4*)(dst + 4 * (size_t)i) = o;
}

// ---------------------------------------------------------------------------
// Batched tiled transpose, dtype-adaptive input, bf16 out.
// ---------------------------------------------------------------------------
__global__ __launch_bounds__(256) void transpose_kernel(
    const void* __restrict__ src, unsigned short* __restrict__ dst,
    int R, int C, const int* __restrict__ flag) {
  __shared__ unsigned short tile[32][33];
  const bool isf = (*flag > 64);
  const int c0 = blockIdx.x * 32, r0 = blockIdx.y * 32;
  const size_t base = (size_t)blockIdx.z * R * C;
  const int tx = threadIdx.x, ty = threadIdx.y;
#pragma unroll
  for (int j = 0; j < 32; j += 8) {
    const size_t idx = base + (size_t)(r0 + ty + j) * C + c0 + tx;
    tile[ty + j][tx] = isf ? f2b(((const float*)src)[idx])
                           : ((const unsigned short*)src)[idx];
  }
  __syncthreads();
#pragma unroll
  for (int j = 0; j < 32; j += 8)
    dst[base + (size_t)(c0 + ty + j) * R + r0 + tx] = tile[tx][ty + j];
}

// bf16-only batched transpose (V [t][h] -> [h][t] per (b,n))
__global__ __launch_bounds__(256) void transpose_bf16_kernel(
    const unsigned short* __restrict__ src, unsigned short* __restrict__ dst,
    int R, int C) {
  __shared__ unsigned short tile[32][33];
  const int c0 = blockIdx.x * 32, r0 = blockIdx.y * 32;
  const size_t base = (size_t)blockIdx.z * R * C;
  const int tx = threadIdx.x, ty = threadIdx.y;
#pragma unroll
  for (int j = 0; j < 32; j += 8)
    tile[ty + j][tx] = src[base + (size_t)(r0 + ty + j) * C + c0 + tx];
  __syncthreads();
#pragma unroll
  for (int j = 0; j < 32; j += 8)
    dst[base + (size_t)(c0 + ty + j) * R + r0 + tx] = tile[tx][ty + j];
}

// ---------------------------------------------------------------------------
// 128x128-tile bf16 GEMM, K=2048, BK=64 (32 MFMA per barrier-pair).
// LDS xor-swizzle: physical chunk = logical chunk ^ (row & 7)  (8 chunks/row)
// -> global_load_lds-compatible AND conflict-free b128 frag reads.
// mode 0: final projection, fp32/bf16 out per flag. mode 1: qkv [s][b][n][t][h].
// ---------------------------------------------------------------------------
__global__ __launch_bounds__(256) void gemm128_kernel(
    const unsigned short* __restrict__ A,
    const unsigned short* __restrict__ Bt,
    void* __restrict__ outp,
    int mode, const int* __restrict__ flag) {
  constexpr int K = D_;
  __shared__ unsigned short As[128 * 64];
  __shared__ unsigned short Bs[128 * 64];
  const int tid = threadIdx.x;
  const int lane = tid & 63;
  const int lr = lane & 15, lq = lane >> 4;
  const int wave = tid >> 6;
  const int wm = (wave >> 1) * 64, wn = (wave & 1) * 64;
  const size_t m0 = (size_t)blockIdx.x * 128;
  const unsigned short* pA = A + m0 * K;
  const unsigned short* pB = Bt + (size_t)blockIdx.y * 128 * K;

  f32x4 acc[4][4] = {};

  // staging: slot s = j*256+tid; row = s>>3 = j*32+(tid>>3); phys chunk = tid&7;
  // global chunk = (tid&7) ^ (row&7) = (tid&7) ^ ((tid>>3)&7)  (same for all j)
  const int cg = (tid & 7) ^ ((tid >> 3) & 7);
  size_t goff[4];
#pragma unroll
  for (int j = 0; j < 4; ++j)
    goff[j] = (size_t)(j * 32 + (tid >> 3)) * K + cg * 8;

  for (int k0 = 0; k0 < K; k0 += 64) {
    __syncthreads();
#pragma unroll
    for (int j = 0; j < 4; ++j) {
      __builtin_amdgcn_global_load_lds((cglobal_void*)(pA + goff[j] + k0),
                                       (lds_void*)(As + (size_t)(j * 256 + tid) * 8), 16, 0, 0);
      __builtin_amdgcn_global_load_lds((cglobal_void*)(pB + goff[j] + k0),
                                       (lds_void*)(Bs + (size_t)(j * 256 + tid) * 8), 16, 0, 0);
    }
    __syncthreads();
#pragma unroll
    for (int kq = 0; kq < 2; ++kq) {
      const int co = (((kq << 2) + lq) ^ (lr & 7)) * 8;
      s16x8 af[4], bfr[4];
#pragma unroll
      for (int mb = 0; mb < 4; ++mb)
        af[mb] = *(const s16x8*)(As + (wm + mb * 16 + lr) * 64 + co);
#pragma unroll
      for (int nb = 0; nb < 4; ++nb)
        bfr[nb] = *(const s16x8*)(Bs + (wn + nb * 16 + lr) * 64 + co);
#pragma unroll
      for (int mb = 0; mb < 4; ++mb)
#pragma unroll
        for (int nb = 0; nb < 4; ++nb)
          acc[mb][nb] = __builtin_amdgcn_mfma_f32_16x16x32_bf16(af[mb], bfr[nb], acc[mb][nb], 0, 0, 0);
    }
  }

  if (mode == 0) {
    const bool isf = (*flag > 64);
#pragma unroll
    for (int mb = 0; mb < 4; ++mb) {
      const size_t r = m0 + wm + mb * 16 + lq * 4;
#pragma unroll
      for (int nb = 0; nb < 4; ++nb) {
        const size_t c = (size_t)blockIdx.y * 128 + wn + nb * 16 + lr;
#pragma unroll
        for (int i = 0; i < 4; ++i) {
          if (isf) ((float*)outp)[(r + i) * D_ + c] = acc[mb][nb][i];
          else ((unsigned short*)outp)[(r + i) * D_ + c] = f2b(acc[mb][nb][i]);
        }
      }
    }
  } else {
    unsigned short* op = (unsigned short*)outp;
    const int s = blockIdx.y >> 4, n = blockIdx.y & 15;
    const size_t SB = (size_t)B_ * N_ * T_ * H_;
#pragma unroll
    for (int mb = 0; mb < 4; ++mb) {
#pragma unroll
      for (int i = 0; i < 4; ++i) {
        const size_t r = m0 + wm + mb * 16 + lq * 4 + i;
        const int b = (int)(r >> 11);
        const int t = (int)(r & 2047);
        const size_t base = s * SB + (size_t)(b * N_ + n) * T_ * H_ + (size_t)t * H_;
#pragma unroll
        for (int nb = 0; nb < 4; ++nb)
          op[base + wn + nb * 16 + lr] = f2b(acc[mb][nb][i]);
      }
    }
  }
}

// ---------------------------------------------------------------------------
// RoPE in place on q,k rows. One wave per 128-elem row; q scaled by H^-0.5.
// ---------------------------------------------------------------------------
__global__ __launch_bounds__(256) void rope_kernel(unsigned short* __restrict__ qk) {
  const int tid = threadIdx.x;
  const int lane = tid & 63;
  const size_t row = (size_t)blockIdx.x * 4 + (tid >> 6);
  const int t = (int)(row & (T_ - 1));
  const int s = (int)(row >> 16);
  unsigned short* p = qk + row * H_;
  float x1 = b2f(p[lane]), x2 = b2f(p[lane + 64]);
  // timescale^-1 = 10000^(-lane/64) = exp2(-lane*log2(10000)/64)
  const float inv_ts = exp2f(-0.20762050f * (float)lane);
  float sv, cv;
  __sincosf((float)t * inv_ts, &sv, &cv);
  float o1 = x1 * cv - x2 * sv;
  float o2 = x2 * cv + x1 * sv;
  if (s == 0) { o1 *= 0.08838834764831845f; o2 *= 0.08838834764831845f; }
  p[lane] = f2b(o1);
  p[lane + 64] = f2b(o2);
}

// ---------------------------------------------------------------------------
// Flash attention, fixed-offset softmax (softcap bounds logits).
// K/V staged via global_load_lds into xor-swizzled unpadded LDS tiles:
//   Ks[64 key][128 h]  : phys chunk16 = logical ^ (key&15)
//   Vt[128 h][64 key]  : phys chunk8  = logical ^ (h&7)
//   Ps (aliases Ks)    : per-wave 16x64, phys chunk8 = logical ^ (row&7)
// p = exp2(-2*C_T*rcp(u+1) + BIAS), u = exp2(a*C_IN): same softmax weights
// (constant absorbed by l). LDS 32 KB.
// ---------------------------------------------------------------------------
__global__ __launch_bounds__(256, 4) void attn_kernel(
    const unsigned short* __restrict__ qkv,
    const unsigned short* __restrict__ vt,
    unsigned short* __restrict__ enc) {
  const int tid = threadIdx.x, lane = tid & 63, wave = tid >> 6;
  const int lr = lane & 15, lq = lane >> 4;
  const int bn = blockIdx.x;
  const int b = bn >> 4, n = bn & 15;
  const int t0 = blockIdx.y * 64;
  const size_t SB = (size_t)B_ * N_ * T_ * H_;
  const unsigned short* qp = qkv + (size_t)bn * T_ * H_;
  const unsigned short* kp = qp + SB;
  const unsigned short* vp = vt + (size_t)bn * T_ * H_;  // [h][t]

  __shared__ unsigned short Ks[64 * 128];
  __shared__ unsigned short Vt[128 * 64];
  unsigned short* Ps = Ks + wave * 1024;  // 16 rows x 64, swizzled

  // staging offsets (lane-invariant across j except row):
  const int cgK = (tid & 15) ^ ((tid >> 4) & 15);   // 16 chunks/row
  const int cgV = (tid & 7) ^ ((tid >> 3) & 7);     // 8 chunks/row
  size_t goffK[4], goffV[4];
#pragma unroll
  for (int j = 0; j < 4; ++j) {
    goffK[j] = (size_t)(j * 16 + (tid >> 4)) * H_ + cgK * 8;
    goffV[j] = (size_t)(j * 32 + (tid >> 3)) * T_ + cgV * 8;
  }

  // Q fragments (A-layout), registers for whole kernel
  s16x8 aq[4];
  {
    const int t = t0 + wave * 16 + lr;
#pragma unroll
    for (int kc = 0; kc < 4; ++kc)
      aq[kc] = *(const s16x8*)(qp + (size_t)t * H_ + kc * 32 + lq * 8);
  }

  f32x4 oacc[8] = {};
  float lp[4] = {0.f, 0.f, 0.f, 0.f};

  const int s_lo = (t0 >= WIN - 1) ? ((t0 - (WIN - 1)) & ~63) : 0;
  constexpr float C_IN = 0.05770780f;     // 2*log2(e)/50
  constexpr float M_SCALE = -144.269504f; // -2*50*log2(e)
  constexpr float M_BIAS = 86.56f;        // keeps p in [2^-58, 2^87]

  for (int s0 = s_lo; s0 <= t0 + 63; s0 += 64) {
    __syncthreads();  // (A) prev-iter Vt/Ps reads done before restage
#pragma unroll
    for (int j = 0; j < 4; ++j) {
      __builtin_amdgcn_global_load_lds((cglobal_void*)(kp + (size_t)s0 * H_ + goffK[j]),
                                       (lds_void*)(Ks + (size_t)(j * 256 + tid) * 8), 16, 0, 0);
      __builtin_amdgcn_global_load_lds((cglobal_void*)(vp + goffV[j] + s0),
                                       (lds_void*)(Vt + (size_t)(j * 256 + tid) * 8), 16, 0, 0);
    }
    __syncthreads();  // (B) staging visible

    // QK^T -> p
    float p[4][4];
#pragma unroll
    for (int sb = 0; sb < 4; ++sb) {
      f32x4 a = {};
#pragma unroll
      for (int kc = 0; kc < 4; ++kc) {
        const int co = (((kc << 2) + lq) ^ lr) * 8;
        s16x8 bk = *(const s16x8*)(Ks + (sb * 16 + lr) * 128 + co);
        a = __builtin_amdgcn_mfma_f32_16x16x32_bf16(aq[kc], bk, a, 0, 0, 0);
      }
#pragma unroll
      for (int i = 0; i < 4; ++i) {
        const float u = exp2f(a[i] * C_IN);
        const float r = __builtin_amdgcn_rcpf(u + 1.0f);
        p[sb][i] = exp2f(fmaf(r, M_SCALE, M_BIAS));
      }
    }

    // mask only boundary tiles (wave-uniform branch)
    const bool interior = (s0 + 63 <= t0) && (s0 >= t0 + 63 - (WIN - 1));
    if (!interior) {
#pragma unroll
      for (int sb = 0; sb < 4; ++sb) {
        const int key = s0 + sb * 16 + lr;
#pragma unroll
        for (int i = 0; i < 4; ++i) {
          const int t = t0 + wave * 16 + lq * 4 + i;
          if (key > t || key < t - (WIN - 1)) p[sb][i] = 0.0f;
        }
      }
    }
#pragma unroll
    for (int sb = 0; sb < 4; ++sb)
#pragma unroll
      for (int i = 0; i < 4; ++i) lp[i] += p[sb][i];

    __syncthreads();  // (C) Ks QK-reads done before Ps overwrite
#pragma unroll
    for (int sb = 0; sb < 4; ++sb)
#pragma unroll
      for (int i = 0; i < 4; ++i) {
        const int row = lq * 4 + i;
        const int cph = ((sb * 2 + (lr >> 3)) ^ (row & 7));
        Ps[row * 64 + cph * 8 + (lr & 7)] = f2b(p[sb][i]);
      }
    __syncthreads();  // (D) Ps visible

    s16x8 ap[2];
#pragma unroll
    for (int kc = 0; kc < 2; ++kc)
      ap[kc] = *(const s16x8*)(Ps + lr * 64 + ((((kc << 2) + lq) ^ (lr & 7)) * 8));

#pragma unroll
    for (int hb = 0; hb < 8; ++hb) {
#pragma unroll
      for (int kc = 0; kc < 2; ++kc) {
        const int co = (((kc << 2) + lq) ^ (lr & 7)) * 8;
        s16x8 bv = *(const s16x8*)(Vt + (hb * 16 + lr) * 64 + co);
        oacc[hb] = __builtin_amdgcn_mfma_f32_16x16x32_bf16(ap[kc], bv, oacc[hb], 0, 0, 0);
      }
    }
  }

  // l: reduce per-lane partials across the 16 lr-lanes
#pragma unroll
  for (int i = 0; i < 4; ++i) {
#pragma unroll
    for (int off = 1; off < 16; off <<= 1)
      lp[i] += __shfl_xor(lp[i], off, 64);
  }

#pragma unroll
  for (int i = 0; i < 4; ++i) {
    const int t = t0 + wave * 16 + lq * 4 + i;
    const float inv = 1.0f / lp[i];
    const size_t rowb = ((size_t)b * T_ + t) * (N_ * H_) + (size_t)n * H_;
#pragma unroll
    for (int hb = 0; hb < 8; ++hb)
      enc[rowb + hb * 16 + lr] = f2b(oacc[hb][i] * inv);
  }
}

// ---------------------------------------------------------------------------
extern "C" void kernel_launch(void* const* d_in, const int* in_sizes, int n_in,
                              void* d_out, int out_size, void* d_ws, size_t ws_size,
                              hipStream_t stream) {
  const void* x     = d_in[0];  // (B,T,D)    fp32 (auto-detected; bf16 hedge)
  const void* w_qkv = d_in[1];  // (3,N,D,H)
  const void* w_out = d_in[2];  // (N,H,D)

  // workspace (88 MB peak, proven safe):
  //   [0,64)          flag
  //   A [64,+16MB)    xc        -> later vt (v transposed, 16MB)
  //   B [+16,+40MB)   wqkvT     -> later enc(16MB) + woutT(8MB)
  //   C [+40,+88MB)   qkv: q(16) k(16) v(16)
  char* wsb = (char*)d_ws;
  int* flag = (int*)wsb;
  const size_t MB = 1048576;
  unsigned short* xc    = (unsigned short*)(wsb + 64);
  unsigned short* wqkvT = (unsigned short*)(wsb + 64 + 16 * MB);
  unsigned short* qkv   = (unsigned short*)(wsb + 64 + 40 * MB);
  unsigned short* vt    = xc;                                        // alias
  unsigned short* enc   = wqkvT;                                     // alias
  unsigned short* woutT = (unsigned short*)(wsb + 64 + 32 * MB);     // alias
  unsigned short* v     = qkv + 2 * (size_t)B_ * N_ * T_ * H_;

  detect_kernel<<<1, 256, 0, stream>>>((const unsigned short*)x, flag);
  convert_x_kernel<<<8192, 256, 0, stream>>>(x, xc, flag, B_ * T_ * D_ / 4);
  transpose_kernel<<<dim3(4, 64, 48), dim3(32, 8), 0, stream>>>(w_qkv, wqkvT, 2048, 128, flag);
  gemm128_kernel<<<dim3(32, 48), 256, 0, stream>>>(xc, wqkvT, qkv, 1, flag);
  rope_kernel<<<32768, 256, 0, stream>>>(qkv);
  transpose_bf16_kernel<<<dim3(4, 64, 32), dim3(32, 8), 0, stream>>>(v, vt, 2048, 128);
  transpose_kernel<<<dim3(64, 64, 1), dim3(32, 8), 0, stream>>>(w_out, woutT, 2048, 2048, flag);
  attn_kernel<<<dim3(32, 32), 256, 0, stream>>>(qkv, vt, enc);
  gemm128_kernel<<<dim3(32, 16), 256, 0, stream>>>(enc, woutT, d_out, 0, flag);
}